// Round 7
// baseline (317.254 us; speedup 1.0000x reference)
//
#include <hip/hip_runtime.h>
#include <hip/hip_bf16.h>

#define NN 50000
#define NE 400000
#define NPAIR 12500        // NE/32: 32 sorted edges per wave-iteration
#define NCH 196            // ceil(50176/256) scan chunks
#define NPAD 50176         // NCH*256

typedef __bf16 bf16_t;
typedef __bf16 bf16x4 __attribute__((ext_vector_type(4)));
typedef __bf16 bf16x8 __attribute__((ext_vector_type(8)));
typedef float  floatx4 __attribute__((ext_vector_type(4)));

static __device__ __forceinline__ floatx4 mfma16(bf16x8 a, bf16x8 b, floatx4 c) {
    return __builtin_amdgcn_mfma_f32_16x16x32_bf16(a, b, c, 0, 0, 0);
}
static __device__ __forceinline__ float sigm_f(float x) {
    return 1.f / (1.f + __expf(-x));
}
static __device__ __forceinline__ float tanh_f(float x) {
    return 1.f - 2.f / (__expf(2.f * x) + 1.f);
}
static __device__ __forceinline__ bf16x8 cvt8(const float* sp) {
    float4 f0 = *(const float4*)sp;
    float4 f1 = *(const float4*)(sp + 4);
    bf16x8 v;
    v[0] = (bf16_t)f0.x; v[1] = (bf16_t)f0.y; v[2] = (bf16_t)f0.z; v[3] = (bf16_t)f0.w;
    v[4] = (bf16_t)f1.x; v[5] = (bf16_t)f1.y; v[6] = (bf16_t)f1.z; v[7] = (bf16_t)f1.w;
    return v;
}

// ---------------------------------------------------------------------------
// prep (fused): bf16 h copy + weight transforms into MFMA-fragment-linear.
// ---------------------------------------------------------------------------
__global__ __launch_bounds__(256) void prep_kernel(
    const float* __restrict__ nf,
    const float* __restrict__ Wm1, const float* __restrict__ Wm2,
    const float* __restrict__ Wx,  const float* __restrict__ Wh,
    const float* __restrict__ Wr1,
    bf16_t* __restrict__ hb,
    bf16_t* __restrict__ W1f, bf16_t* __restrict__ W2f,
    bf16_t* __restrict__ Wxt, bf16_t* __restrict__ Wht,
    bf16_t* __restrict__ Wr1f)
{
    int u = blockIdx.x * 256 + threadIdx.x;
    if (u < 800000) {          // hb: 4 elems per thread
        float4 v = *(const float4*)(nf + (size_t)u * 4);
        bf16x4 o;
        o[0] = (bf16_t)v.x; o[1] = (bf16_t)v.y; o[2] = (bf16_t)v.z; o[3] = (bf16_t)v.w;
        *(bf16x4*)(hb + (size_t)u * 4) = o;
        return;
    }
    u -= 800000;
    if (u < 20480) {
        int j = u & 7, l = (u >> 3) & 63, rem = u >> 9;   // rem 0..39
        int ks = rem % 5, nt = rem / 5;
        int n = nt * 16 + (l & 15);
        int k = ks * 32 + (l >> 4) * 8 + j;
        W1f[u] = (k < 136) ? (bf16_t)Wm1[k * 128 + n] : (bf16_t)0.f;
        return;
    }
    u -= 20480;
    if (u < 8192) {
        int j = u & 7, l = (u >> 3) & 63, rem = u >> 9;   // rem 0..15
        int kg = rem & 3, nt = rem >> 2;
        int n = nt * 16 + (l & 15);
        int k = kg * 32 + (l >> 4) * 8 + j;
        W2f[u] = (bf16_t)Wm2[k * 64 + n];
        return;
    }
    u -= 8192;
    if (u < 12288) {
        int n = u >> 6, k = u & 63;
        Wxt[u] = (bf16_t)Wx[k * 192 + n];
        return;
    }
    u -= 12288;
    if (u < 12288) {
        int n = u >> 6, k = u & 63;
        Wht[u] = (bf16_t)Wh[k * 192 + n];
        return;
    }
    u -= 12288;
    if (u < 8192) {            // Wr1f
        int j = u & 7, l = (u >> 3) & 63, rem = u >> 9;   // rem 0..15
        int kg = rem & 1, nt = rem >> 1;
        int n = nt * 16 + (l & 15);
        int k = kg * 32 + (l >> 4) * 8 + j;
        Wr1f[u] = (bf16_t)Wr1[k * 128 + n];
    }
}

// ---------------------------------------------------------------------------
// CSR build: hist -> scan -> scatter (permute srcs/dsts/ef->bf16, dst-sorted)
// ---------------------------------------------------------------------------
__global__ __launch_bounds__(256) void hist_kernel(
    const int* __restrict__ edst, int* __restrict__ deg)
{
    int e = blockIdx.x * 256 + threadIdx.x;
    if (e < NE) atomicAdd(&deg[edst[e]], 1);
}

__global__ __launch_bounds__(256) void scanA_kernel(
    const int* __restrict__ deg, int* __restrict__ chunkSums)
{
    __shared__ int s[256];
    int i = blockIdx.x * 256 + threadIdx.x;
    s[threadIdx.x] = deg[i];
    __syncthreads();
    for (int st = 128; st >= 1; st >>= 1) {
        if (threadIdx.x < st) s[threadIdx.x] += s[threadIdx.x + st];
        __syncthreads();
    }
    if (threadIdx.x == 0) chunkSums[blockIdx.x] = s[0];
}

__global__ __launch_bounds__(256) void scanB_kernel(
    const int* __restrict__ chunkSums, int* __restrict__ chunkOff)
{
    __shared__ int s[256];
    int t = threadIdx.x;
    int v = (t < NCH) ? chunkSums[t] : 0;
    s[t] = v;
    __syncthreads();
    for (int st = 1; st < 256; st <<= 1) {
        int add = (t >= st) ? s[t - st] : 0;
        __syncthreads();
        s[t] += add;
        __syncthreads();
    }
    if (t < NCH) chunkOff[t] = s[t] - v;   // exclusive
}

__global__ __launch_bounds__(256) void scanC_kernel(
    const int* __restrict__ deg, const int* __restrict__ chunkOff,
    int* __restrict__ cursor)
{
    __shared__ int s[256];
    int t = threadIdx.x;
    int i = blockIdx.x * 256 + t;
    int v = deg[i];
    s[t] = v;
    __syncthreads();
    for (int st = 1; st < 256; st <<= 1) {
        int add = (t >= st) ? s[t - st] : 0;
        __syncthreads();
        s[t] += add;
        __syncthreads();
    }
    cursor[i] = chunkOff[blockIdx.x] + s[t] - v;   // exclusive
}

__global__ __launch_bounds__(256) void scatter_kernel(
    const int* __restrict__ esrc, const int* __restrict__ edst,
    const float* __restrict__ ef,
    int* __restrict__ cursor, int* __restrict__ srcs, int* __restrict__ dsts,
    bf16_t* __restrict__ efpb)
{
    int e = blockIdx.x * 256 + threadIdx.x;
    if (e >= NE) return;
    int d = edst[e];
    int p = atomicAdd(&cursor[d], 1);    // cursor ends at row-end offsets
    srcs[p] = esrc[e];
    dsts[p] = d;
    float4 a = *(const float4*)(ef + (size_t)e * 8);
    float4 b = *(const float4*)(ef + (size_t)e * 8 + 4);
    bf16x8 v;
    v[0] = (bf16_t)a.x; v[1] = (bf16_t)a.y; v[2] = (bf16_t)a.z; v[3] = (bf16_t)a.w;
    v[4] = (bf16_t)b.x; v[5] = (bf16_t)b.y; v[6] = (bf16_t)b.z; v[7] = (bf16_t)b.w;
    *(bf16x8*)(efpb + (size_t)p * 8) = v;
}

// ---------------------------------------------------------------------------
// edge kernel v19 == v17 exactly (2-deep pipeline, scalar logical mb stores;
// measured <41.3us). v18's packed epilogue kept FETCH/WRITE identical but
// cost +17us pure stall (VGPR 100->112; evidence: scheduler sank the
// prefetch GATHER below the epilogue, breaking latency coverage) — reverted.
// ---------------------------------------------------------------------------
__global__ __launch_bounds__(256) void edge_kernel(
    const bf16_t* __restrict__ hb, const bf16_t* __restrict__ efpb,
    const int* __restrict__ srcs, const int* __restrict__ dsts,
    const bf16_t* __restrict__ W1f, const bf16_t* __restrict__ W2f,
    const float* __restrict__ b1f, const float* __restrict__ b2f,
    bf16_t* __restrict__ mb)
{
    __shared__ __attribute__((aligned(16))) bf16_t w1s[20480];      // 40960 B
    __shared__ __attribute__((aligned(16))) bf16_t w2s[8192];       // 16384 B
    __shared__ __attribute__((aligned(16))) bf16_t hq[4][32 * 36];  //  9216 B

    const int tid = threadIdx.x;
    {
        const uint4* s1 = (const uint4*)W1f;
        uint4* d1 = (uint4*)w1s;
        #pragma unroll
        for (int i = 0; i < 10; i++) d1[tid + i * 256] = s1[tid + i * 256];
        const uint4* s2 = (const uint4*)W2f;
        uint4* d2 = (uint4*)w2s;
        #pragma unroll
        for (int i = 0; i < 4; i++) d2[tid + i * 256] = s2[tid + i * 256];
    }
    __syncthreads();

    const int lane = tid & 63;
    const int wv   = tid >> 6;
    const int l15  = lane & 15;
    const int quad = lane >> 4;

    float b1r[8], b2r[4];
    #pragma unroll
    for (int nt = 0; nt < 8; nt++) b1r[nt] = b1f[nt * 16 + l15];
    #pragma unroll
    for (int nt = 0; nt < 4; nt++) b2r[nt] = b2f[nt * 16 + l15];

    const int WTOT = gridDim.x * 4;

    // idx layout: [0]=src0,[1]=dst0,[2]=src1,[3]=dst1 (rows l15 / 16+l15)
    auto LDIDX = [&](int pp, int* idx) {
        int b = pp * 32;
        idx[0] = srcs[b + l15];       idx[1] = dsts[b + l15];
        idx[2] = srcs[b + 16 + l15];  idx[3] = dsts[b + 16 + l15];
    };
    // af layout: [0..3]=grp0 src lo/hi,dst lo/hi, [4]=grp0 ef,
    //            [5..8]=grp1 src lo/hi,dst lo/hi, [9]=grp1 ef
    auto GATHER = [&](const int* idx, int pp, bf16x8* af) {
        const bf16_t* sp0 = hb + (size_t)idx[0] * 64 + quad * 8;
        const bf16_t* dp0 = hb + (size_t)idx[1] * 64 + quad * 8;
        const bf16_t* sp1 = hb + (size_t)idx[2] * 64 + quad * 8;
        const bf16_t* dp1 = hb + (size_t)idx[3] * 64 + quad * 8;
        af[0] = *(const bf16x8*)sp0;  af[1] = *(const bf16x8*)(sp0 + 32);
        af[2] = *(const bf16x8*)dp0;  af[3] = *(const bf16x8*)(dp0 + 32);
        af[5] = *(const bf16x8*)sp1;  af[6] = *(const bf16x8*)(sp1 + 32);
        af[7] = *(const bf16x8*)dp1;  af[8] = *(const bf16x8*)(dp1 + 32);
        if (quad == 0) {
            int b = pp * 32;
            af[4] = *(const bf16x8*)(efpb + (size_t)(b + l15) * 8);
            af[9] = *(const bf16x8*)(efpb + (size_t)(b + 16 + l15) * 8);
        }
    };
    auto COMPSTORE = [&](const bf16x8* af, int pcur) {
        floatx4 oa0[4], oa1[4];
        #pragma unroll
        for (int nt = 0; nt < 4; nt++) {
            oa0[nt].x=0.f; oa0[nt].y=0.f; oa0[nt].z=0.f; oa0[nt].w=0.f;
            oa1[nt].x=0.f; oa1[nt].y=0.f; oa1[nt].z=0.f; oa1[nt].w=0.f;
        }
        #pragma unroll
        for (int q = 0; q < 4; q++) {
            floatx4 ac0[2], ac1[2];
            #pragma unroll
            for (int nt = 0; nt < 2; nt++) {
                ac0[nt].x=0.f; ac0[nt].y=0.f; ac0[nt].z=0.f; ac0[nt].w=0.f;
                ac1[nt].x=0.f; ac1[nt].y=0.f; ac1[nt].z=0.f; ac1[nt].w=0.f;
            }
            #pragma unroll
            for (int nt = 0; nt < 2; nt++) {
                int gnt = q * 2 + nt;
                #pragma unroll
                for (int ks = 0; ks < 5; ks++) {
                    bf16x8 b = *(const bf16x8*)(w1s + ((gnt * 5 + ks) * 64 + lane) * 8);
                    ac0[nt] = mfma16(af[ks], b, ac0[nt]);
                    ac1[nt] = mfma16(af[5 + ks], b, ac1[nt]);
                }
            }
            #pragma unroll
            for (int nt = 0; nt < 2; nt++) {
                float bb = b1r[q * 2 + nt];
                #pragma unroll
                for (int r = 0; r < 4; r++) {
                    float v0 = fmaxf(ac0[nt][r] + bb, 0.f);
                    float v1 = fmaxf(ac1[nt][r] + bb, 0.f);
                    hq[wv][(quad * 4 + r) * 36 + nt * 16 + l15]      = (bf16_t)v0;
                    hq[wv][(16 + quad * 4 + r) * 36 + nt * 16 + l15] = (bf16_t)v1;
                }
            }
            // same-wave write->read (compiler lgkmcnt)
            bf16x8 hf0 = *(const bf16x8*)(hq[wv] + l15 * 36 + quad * 8);
            bf16x8 hf1 = *(const bf16x8*)(hq[wv] + (16 + l15) * 36 + quad * 8);
            #pragma unroll
            for (int nt = 0; nt < 4; nt++) {
                bf16x8 w2 = *(const bf16x8*)(w2s + ((nt * 4 + q) * 64 + lane) * 8);
                oa0[nt] = mfma16(hf0, w2, oa0[nt]);
                oa1[nt] = mfma16(hf1, w2, oa1[nt]);
            }
        }
        // epilogue: plain bf16 stores of m (+b2), sorted edge order
        int base = pcur * 32;
        #pragma unroll
        for (int nt = 0; nt < 4; nt++) {
            int col = nt * 16 + l15;
            float bb = b2r[nt];
            #pragma unroll
            for (int r = 0; r < 4; r++) {
                int row0 = base + quad * 4 + r;
                int row1 = base + 16 + quad * 4 + r;
                mb[(size_t)row0 * 64 + col] = (bf16_t)(oa0[nt][r] + bb);
                mb[(size_t)row1 * 64 + col] = (bf16_t)(oa1[nt][r] + bb);
            }
        }
    };

    int p = blockIdx.x * 4 + wv;           // current pair index
    int iA[4], iB[4];
    bf16x8 afA[10], afB[10];
    if (quad != 0) {
        #pragma unroll
        for (int q = 0; q < 8; q++) {
            afA[4][q] = (bf16_t)0.f; afA[9][q] = (bf16_t)0.f;
            afB[4][q] = (bf16_t)0.f; afB[9][q] = (bf16_t)0.f;
        }
    }

    // prologue: gather pair-0 into afA; indices for pair-1 into iB
    LDIDX(p, iA);
    GATHER(iA, p, afA);
    int pn = p + WTOT;
    int pp = (pn < NPAIR) ? pn : p;        // clamped, in-bounds
    LDIDX(pp, iB);

    while (true) {
        // phase A: consume afA(pair p); issue gather(iB@pp)->afB; idx 2-ahead->iA
        GATHER(iB, pp, afB);
        {
            int pn2 = pn + WTOT;
            int pq  = (pn2 < NPAIR) ? pn2 : pp;
            LDIDX(pq, iA);
            COMPSTORE(afA, p);
            if (pn >= NPAIR) break;
            p = pn; pn = pn2; pp = pq;
        }
        // phase B: consume afB(pair p); issue gather(iA@pp)->afA; idx 2-ahead->iB
        GATHER(iA, pp, afA);
        {
            int pn2 = pn + WTOT;
            int pq  = (pn2 < NPAIR) ? pn2 : pp;
            LDIDX(pq, iB);
            COMPSTORE(afB, p);
            if (pn >= NPAIR) break;
            p = pn; pn = pn2; pp = pq;
        }
    }
}

// ---------------------------------------------------------------------------
// agg kernel v19: vectorized CSR gather-sum on the LOGICAL mb layout.
// Lane (quad,l15) loads bf16x4 at mb[e*64 + l15*4] = logical cols
// 4*l15..4*l15+3 of row e; quads stride rows -> 4 rows (4 full 128B lines)
// per load instruction, 4x fewer issues than scalar. Cross-quad shfl_xor
// reduce; quad 0 writes one bf16x4 per lane (cols 4*l15..4*l15+3).
// mb (51.2MB) fits L3 -> reads run at L3 speed after edge writes it.
// No layout permutation needed anywhere.
// ---------------------------------------------------------------------------
__global__ __launch_bounds__(256) void agg_kernel(
    const bf16_t* __restrict__ mb, const int* __restrict__ deg,
    const int* __restrict__ cursor, bf16_t* __restrict__ aggb)
{
    const int node = blockIdx.x * 4 + (threadIdx.x >> 6);
    if (node >= NN) return;
    const int lane = threadIdx.x & 63;
    const int l15  = lane & 15;
    const int quad = lane >> 4;
    int dg  = deg[node];
    int end = cursor[node];
    int st  = end - dg;
    float a0 = 0.f, a1 = 0.f, a2 = 0.f, a3 = 0.f;
    for (int e = st + quad; e < end; e += 4) {
        bf16x4 v = *(const bf16x4*)(mb + (size_t)e * 64 + l15 * 4);
        a0 += (float)v[0]; a1 += (float)v[1]; a2 += (float)v[2]; a3 += (float)v[3];
    }
    a0 += __shfl_xor(a0, 16, 64); a0 += __shfl_xor(a0, 32, 64);
    a1 += __shfl_xor(a1, 16, 64); a1 += __shfl_xor(a1, 32, 64);
    a2 += __shfl_xor(a2, 16, 64); a2 += __shfl_xor(a2, 32, 64);
    a3 += __shfl_xor(a3, 16, 64); a3 += __shfl_xor(a3, 32, 64);
    if (quad == 0) {
        bf16x4 o;
        o[0] = (bf16_t)a0; o[1] = (bf16_t)a1; o[2] = (bf16_t)a2; o[3] = (bf16_t)a3;
        *(bf16x4*)(aggb + (size_t)node * 64 + l15 * 4) = o;
    }
}

// ---------------------------------------------------------------------------
// GRU (MFMA): 64 nodes/block, 16/wave. agg input bf16 (logical layout).
// LAST=0: emits fp32 h + bf16 hb. LAST=1: fused readout MLP.
// ---------------------------------------------------------------------------
template<int LAST>
__global__ __launch_bounds__(256) void gru_kernel(
    const bf16_t* __restrict__ aggb, const float* __restrict__ h_in,
    float* __restrict__ h_out, bf16_t* __restrict__ hb_out,
    const bf16_t* __restrict__ Wxt, const bf16_t* __restrict__ Wht,
    const float* __restrict__ bg,
    const bf16_t* __restrict__ Wr1f, const float* __restrict__ br1,
    const float* __restrict__ Wr2, const float* __restrict__ br2,
    float* __restrict__ out)
{
    __shared__ __attribute__((aligned(16))) float  shd[64 * 68];    // 17408 B
    __shared__ __attribute__((aligned(16))) bf16_t hb2[4][16 * 72]; //  9216 B
    const int tid = threadIdx.x;
    const int n0  = blockIdx.x * 64;

    for (int idx = tid; idx < 64 * 16; idx += 256) {
        int i = idx >> 4, c = (idx & 15) * 4;
        int n = n0 + i; if (n >= NN) n = NN - 1;
        *(float4*)&shd[i * 68 + c] = *(const float4*)(h_in + (size_t)n * 64 + c);
    }
    __syncthreads();

    const int lane = tid & 63;
    const int wv   = tid >> 6;
    const int l15  = lane & 15;
    const int quad = lane >> 4;
    const int rowA = wv * 16 + l15;
    int nA = n0 + rowA; if (nA >= NN) nA = NN - 1;

    bf16x8 ax[2], ah[2];
    ax[0] = *(const bf16x8*)(aggb + (size_t)nA * 64 + quad * 8);
    ax[1] = *(const bf16x8*)(aggb + (size_t)nA * 64 + quad * 8 + 32);
    {
        const float* hp = shd + rowA * 68 + quad * 8;
        ah[0] = cvt8(hp);
        ah[1] = cvt8(hp + 32);
    }

    floatx4 az[4], ar[4], axh[4], ahh[4];
    #pragma unroll
    for (int nt = 0; nt < 4; nt++) {
        az[nt].x=0.f; az[nt].y=0.f; az[nt].z=0.f; az[nt].w=0.f;
        ar[nt].x=0.f; ar[nt].y=0.f; ar[nt].z=0.f; ar[nt].w=0.f;
        axh[nt].x=0.f; axh[nt].y=0.f; axh[nt].z=0.f; axh[nt].w=0.f;
        ahh[nt].x=0.f; ahh[nt].y=0.f; ahh[nt].z=0.f; ahh[nt].w=0.f;
    }
    #pragma unroll
    for (int nt = 0; nt < 4; nt++) {
        const bf16_t* bx_z = Wxt + (nt * 16 + l15) * 64 + quad * 8;
        const bf16_t* bh_z = Wht + (nt * 16 + l15) * 64 + quad * 8;
        const bf16_t* bx_r = bx_z + 64 * 64;
        const bf16_t* bh_r = bh_z + 64 * 64;
        const bf16_t* bx_h = bx_z + 128 * 64;
        const bf16_t* bh_h = bh_z + 128 * 64;
        az[nt]  = mfma16(ax[0], *(const bf16x8*)bx_z,        az[nt]);
        az[nt]  = mfma16(ax[1], *(const bf16x8*)(bx_z + 32), az[nt]);
        az[nt]  = mfma16(ah[0], *(const bf16x8*)bh_z,        az[nt]);
        az[nt]  = mfma16(ah[1], *(const bf16x8*)(bh_z + 32), az[nt]);
        ar[nt]  = mfma16(ax[0], *(const bf16x8*)bx_r,        ar[nt]);
        ar[nt]  = mfma16(ax[1], *(const bf16x8*)(bx_r + 32), ar[nt]);
        ar[nt]  = mfma16(ah[0], *(const bf16x8*)bh_r,        ar[nt]);
        ar[nt]  = mfma16(ah[1], *(const bf16x8*)(bh_r + 32), ar[nt]);
        axh[nt] = mfma16(ax[0], *(const bf16x8*)bx_h,        axh[nt]);
        axh[nt] = mfma16(ax[1], *(const bf16x8*)(bx_h + 32), axh[nt]);
        ahh[nt] = mfma16(ah[0], *(const bf16x8*)bh_h,        ahh[nt]);
        ahh[nt] = mfma16(ah[1], *(const bf16x8*)(bh_h + 32), ahh[nt]);
    }

    #pragma unroll
    for (int nt = 0; nt < 4; nt++) {
        int j = nt * 16 + l15;
        float bz = bg[j], brr = bg[64 + j], bh = bg[128 + j];
        #pragma unroll
        for (int r = 0; r < 4; r++) {
            int lrow = wv * 16 + quad * 4 + r;
            int n = n0 + lrow;
            float z  = sigm_f(az[nt][r] + bz);
            float rr = sigm_f(ar[nt][r] + brr);
            float hc = tanh_f(axh[nt][r] + bh + rr * ahh[nt][r]);
            float hold = shd[lrow * 68 + j];
            float hnew = z * hold + (1.f - z) * hc;
            if (LAST) {
                hb2[wv][(quad * 4 + r) * 72 + j] = (bf16_t)hnew;
            } else if (n < NN) {
                h_out[(size_t)n * 64 + j]  = hnew;
                hb_out[(size_t)n * 64 + j] = (bf16_t)hnew;
            }
        }
    }

    if (LAST) {
        bf16x8 a0 = *(const bf16x8*)(hb2[wv] + l15 * 72 + quad * 8);
        bf16x8 a1 = *(const bf16x8*)(hb2[wv] + l15 * 72 + quad * 8 + 32);
        floatx4 accR[8];
        #pragma unroll
        for (int nt = 0; nt < 8; nt++) { accR[nt].x=0.f; accR[nt].y=0.f; accR[nt].z=0.f; accR[nt].w=0.f; }
        #pragma unroll
        for (int nt = 0; nt < 8; nt++) {
            bf16x8 b0 = *(const bf16x8*)(Wr1f + ((nt * 2 + 0) * 64 + lane) * 8);
            bf16x8 b1 = *(const bf16x8*)(Wr1f + ((nt * 2 + 1) * 64 + lane) * 8);
            accR[nt] = mfma16(a0, b0, accR[nt]);
            accR[nt] = mfma16(a1, b1, accR[nt]);
        }
        float br1r[8], wr2r[8];
        #pragma unroll
        for (int nt = 0; nt < 8; nt++) {
            br1r[nt] = br1[nt * 16 + l15];
            wr2r[nt] = Wr2[nt * 16 + l15];
        }
        float br2v = br2[0];
        #pragma unroll
        for (int r = 0; r < 4; r++) {
            float p = 0.f;
            #pragma unroll
            for (int nt = 0; nt < 8; nt++)
                p += fmaxf(accR[nt][r] + br1r[nt], 0.f) * wr2r[nt];
            p += __shfl_xor(p, 1, 64);
            p += __shfl_xor(p, 2, 64);
            p += __shfl_xor(p, 4, 64);
            p += __shfl_xor(p, 8, 64);
            if (l15 == 0) {
                int n = n0 + wv * 16 + quad * 4 + r;
                if (n < NN) out[n] = p + br2v;
            }
        }
    }
}

// ---------------------------------------------------------------------------
extern "C" void kernel_launch(void* const* d_in, const int* in_sizes, int n_in,
                              void* d_out, int out_size, void* d_ws, size_t ws_size,
                              hipStream_t stream)
{
    const float* nf  = (const float*)d_in[0];
    const float* ef  = (const float*)d_in[1];
    const int* esrc  = (const int*)d_in[2];
    const int* edst  = (const int*)d_in[3];
    const float* Wm1 = (const float*)d_in[4];
    const float* bm1 = (const float*)d_in[5];
    const float* Wm2 = (const float*)d_in[6];
    const float* bm2 = (const float*)d_in[7];
    const float* Wx  = (const float*)d_in[8];
    const float* Wh  = (const float*)d_in[9];
    const float* bg  = (const float*)d_in[10];
    const float* Wr1 = (const float*)d_in[11];
    const float* br1 = (const float*)d_in[12];
    const float* Wr2 = (const float*)d_in[13];
    const float* br2 = (const float*)d_in[14];

    char* ws = (char*)d_ws;
    float*  hbuf   = (float*)(ws);                   // 12,800,000
    bf16_t* hb     = (bf16_t*)(ws + 12800000);       // 6,400,000
    bf16_t* W1f    = (bf16_t*)(ws + 19200000);       // 40,960
    bf16_t* W2f    = (bf16_t*)(ws + 19240960);       // 16,384
    bf16_t* Wxt    = (bf16_t*)(ws + 19257344);       // 24,576
    bf16_t* Wht    = (bf16_t*)(ws + 19281920);       // 24,576
    bf16_t* Wr1f   = (bf16_t*)(ws + 19306496);       // 16,384
    int*    srcs   = (int*)(ws + 19322880);          // 1,600,000
    int*    dsts   = (int*)(ws + 20922880);          // 1,600,000
    bf16_t* efpb   = (bf16_t*)(ws + 22522880);       // 6,400,000
    int*    deg    = (int*)(ws + 28922880);          // 200,704
    int*    cursor = (int*)(ws + 29123584);          // 200,704
    int*    chunkS = (int*)(ws + 29324288);          // 1,024
    int*    chunkO = (int*)(ws + 29325312);          // 1,024
    bf16_t* aggb   = (bf16_t*)(ws + 29326336);       // 6,400,000
    bf16_t* mb     = (bf16_t*)(ws + 35726336);       // 51,200,000

    prep_kernel<<<3365, 256, 0, stream>>>(nf, Wm1, Wm2, Wx, Wh, Wr1,
                                          hb, W1f, W2f, Wxt, Wht, Wr1f);

    // CSR build (same work every call)
    hipMemsetAsync(deg, 0, (size_t)NPAD * 4, stream);
    hist_kernel<<<(NE + 255) / 256, 256, 0, stream>>>(edst, deg);
    scanA_kernel<<<NCH, 256, 0, stream>>>(deg, chunkS);
    scanB_kernel<<<1, 256, 0, stream>>>(chunkS, chunkO);
    scanC_kernel<<<NCH, 256, 0, stream>>>(deg, chunkO, cursor);
    scatter_kernel<<<(NE + 255) / 256, 256, 0, stream>>>(esrc, edst, ef, cursor,
                                                         srcs, dsts, efpb);

    // step 0
    edge_kernel<<<1024, 256, 0, stream>>>(hb, efpb, srcs, dsts,
                                          W1f, W2f, bm1, bm2, mb);
    agg_kernel<<<(NN + 3) / 4, 256, 0, stream>>>(mb, deg, cursor, aggb);
    gru_kernel<0><<<(NN + 63) / 64, 256, 0, stream>>>(
        aggb, nf, hbuf, hb, Wxt, Wht, bg, Wr1f, br1, Wr2, br2, (float*)d_out);
    // step 1
    edge_kernel<<<1024, 256, 0, stream>>>(hb, efpb, srcs, dsts,
                                          W1f, W2f, bm1, bm2, mb);
    agg_kernel<<<(NN + 3) / 4, 256, 0, stream>>>(mb, deg, cursor, aggb);
    gru_kernel<1><<<(NN + 63) / 64, 256, 0, stream>>>(
        aggb, hbuf, nullptr, nullptr, Wxt, Wht, bg, Wr1f, br1, Wr2, br2,
        (float*)d_out);
}

// Round 8
// 311.487 us; speedup vs baseline: 1.0185x; 1.0185x over previous
//
#include <hip/hip_runtime.h>
#include <hip/hip_bf16.h>

#define NN 50000
#define NE 400000
#define NPAIR 12500        // NE/32: 32 sorted edges per wave-iteration
#define NCH 196            // ceil(50176/256) scan chunks
#define NPAD 50176         // NCH*256

typedef __bf16 bf16_t;
typedef __bf16 bf16x4 __attribute__((ext_vector_type(4)));
typedef __bf16 bf16x8 __attribute__((ext_vector_type(8)));
typedef float  floatx4 __attribute__((ext_vector_type(4)));

static __device__ __forceinline__ floatx4 mfma16(bf16x8 a, bf16x8 b, floatx4 c) {
    return __builtin_amdgcn_mfma_f32_16x16x32_bf16(a, b, c, 0, 0, 0);
}
static __device__ __forceinline__ float sigm_f(float x) {
    return 1.f / (1.f + __expf(-x));
}
static __device__ __forceinline__ float tanh_f(float x) {
    return 1.f - 2.f / (__expf(2.f * x) + 1.f);
}
static __device__ __forceinline__ bf16x8 cvt8(const float* sp) {
    float4 f0 = *(const float4*)sp;
    float4 f1 = *(const float4*)(sp + 4);
    bf16x8 v;
    v[0] = (bf16_t)f0.x; v[1] = (bf16_t)f0.y; v[2] = (bf16_t)f0.z; v[3] = (bf16_t)f0.w;
    v[4] = (bf16_t)f1.x; v[5] = (bf16_t)f1.y; v[6] = (bf16_t)f1.z; v[7] = (bf16_t)f1.w;
    return v;
}

// ---------------------------------------------------------------------------
// prep (fused): bf16 h copy + weight transforms + degree histogram (tail).
// Weight layouts identical to v19 (NO sigma perm on W2f). Histogram fusion
// saves one launch; its atomics overlap the copy work. deg must be zeroed
// (memsetAsync) BEFORE this kernel.
// ---------------------------------------------------------------------------
__global__ __launch_bounds__(256) void prep_kernel(
    const float* __restrict__ nf,
    const float* __restrict__ Wm1, const float* __restrict__ Wm2,
    const float* __restrict__ Wx,  const float* __restrict__ Wh,
    const float* __restrict__ Wr1,
    const int* __restrict__ edst, int* __restrict__ deg,
    bf16_t* __restrict__ hb,
    bf16_t* __restrict__ W1f, bf16_t* __restrict__ W2f,
    bf16_t* __restrict__ Wxt, bf16_t* __restrict__ Wht,
    bf16_t* __restrict__ Wr1f)
{
    int u = blockIdx.x * 256 + threadIdx.x;
    if (u < 800000) {          // hb: 4 elems per thread
        float4 v = *(const float4*)(nf + (size_t)u * 4);
        bf16x4 o;
        o[0] = (bf16_t)v.x; o[1] = (bf16_t)v.y; o[2] = (bf16_t)v.z; o[3] = (bf16_t)v.w;
        *(bf16x4*)(hb + (size_t)u * 4) = o;
        return;
    }
    u -= 800000;
    if (u < 20480) {
        int j = u & 7, l = (u >> 3) & 63, rem = u >> 9;   // rem 0..39
        int ks = rem % 5, nt = rem / 5;
        int n = nt * 16 + (l & 15);
        int k = ks * 32 + (l >> 4) * 8 + j;
        W1f[u] = (k < 136) ? (bf16_t)Wm1[k * 128 + n] : (bf16_t)0.f;
        return;
    }
    u -= 20480;
    if (u < 8192) {
        int j = u & 7, l = (u >> 3) & 63, rem = u >> 9;   // rem 0..15
        int kg = rem & 3, nt = rem >> 2;
        int n = nt * 16 + (l & 15);
        int k = kg * 32 + (l >> 4) * 8 + j;
        W2f[u] = (bf16_t)Wm2[k * 64 + n];
        return;
    }
    u -= 8192;
    if (u < 12288) {
        int n = u >> 6, k = u & 63;
        Wxt[u] = (bf16_t)Wx[k * 192 + n];
        return;
    }
    u -= 12288;
    if (u < 12288) {
        int n = u >> 6, k = u & 63;
        Wht[u] = (bf16_t)Wh[k * 192 + n];
        return;
    }
    u -= 12288;
    if (u < 8192) {            // Wr1f
        int j = u & 7, l = (u >> 3) & 63, rem = u >> 9;   // rem 0..15
        int kg = rem & 1, nt = rem >> 1;
        int n = nt * 16 + (l & 15);
        int k = kg * 32 + (l >> 4) * 8 + j;
        Wr1f[u] = (bf16_t)Wr1[k * 128 + n];
        return;
    }
    u -= 8192;
    if (u < NE) atomicAdd(&deg[edst[u]], 1);   // fused histogram
}

// ---------------------------------------------------------------------------
// CSR build: scanA -> scanC (self-prefix) -> scatter. scanB eliminated:
// each scanC block computes its own chunk-prefix by reducing
// chunkSums[0..bid-1] (<=196 values) with one 256-thread tree.
// ---------------------------------------------------------------------------
__global__ __launch_bounds__(256) void scanA_kernel(
    const int* __restrict__ deg, int* __restrict__ chunkSums)
{
    __shared__ int s[256];
    int i = blockIdx.x * 256 + threadIdx.x;
    s[threadIdx.x] = deg[i];
    __syncthreads();
    for (int st = 128; st >= 1; st >>= 1) {
        if (threadIdx.x < st) s[threadIdx.x] += s[threadIdx.x + st];
        __syncthreads();
    }
    if (threadIdx.x == 0) chunkSums[blockIdx.x] = s[0];
}

__global__ __launch_bounds__(256) void scanC_kernel(
    const int* __restrict__ deg, const int* __restrict__ chunkSums,
    int* __restrict__ cursor)
{
    __shared__ int s[256];
    __shared__ int baseS;
    const int t   = threadIdx.x;
    const int bid = blockIdx.x;

    // block-wide sum of chunkSums[0..bid-1]  (bid <= 195 < 256)
    s[t] = (t < bid) ? chunkSums[t] : 0;
    __syncthreads();
    for (int st = 128; st >= 1; st >>= 1) {
        if (t < st) s[t] += s[t + st];
        __syncthreads();
    }
    if (t == 0) baseS = s[0];
    __syncthreads();
    const int base = baseS;

    // local exclusive scan of this chunk's degrees
    int i = bid * 256 + t;
    int v = deg[i];
    __syncthreads();           // all reads of s in reduce done before reuse
    s[t] = v;
    __syncthreads();
    for (int st = 1; st < 256; st <<= 1) {
        int add = (t >= st) ? s[t - st] : 0;
        __syncthreads();
        s[t] += add;
        __syncthreads();
    }
    cursor[i] = base + s[t] - v;   // exclusive
}

__global__ __launch_bounds__(256) void scatter_kernel(
    const int* __restrict__ esrc, const int* __restrict__ edst,
    const float* __restrict__ ef,
    int* __restrict__ cursor, int* __restrict__ srcs, int* __restrict__ dsts,
    bf16_t* __restrict__ efpb)
{
    int e = blockIdx.x * 256 + threadIdx.x;
    if (e >= NE) return;
    int d = edst[e];
    int p = atomicAdd(&cursor[d], 1);    // cursor ends at row-end offsets
    srcs[p] = esrc[e];
    dsts[p] = d;
    float4 a = *(const float4*)(ef + (size_t)e * 8);
    float4 b = *(const float4*)(ef + (size_t)e * 8 + 4);
    bf16x8 v;
    v[0] = (bf16_t)a.x; v[1] = (bf16_t)a.y; v[2] = (bf16_t)a.z; v[3] = (bf16_t)a.w;
    v[4] = (bf16_t)b.x; v[5] = (bf16_t)b.y; v[6] = (bf16_t)b.z; v[7] = (bf16_t)b.w;
    *(bf16x8*)(efpb + (size_t)p * 8) = v;
}

// ---------------------------------------------------------------------------
// edge kernel == v17/v19 exactly (2-deep pipeline, scalar logical mb stores;
// proven <42us, FETCH 26MB / WRITE 50MB exact, 0 conflicts). Untouched.
// ---------------------------------------------------------------------------
__global__ __launch_bounds__(256) void edge_kernel(
    const bf16_t* __restrict__ hb, const bf16_t* __restrict__ efpb,
    const int* __restrict__ srcs, const int* __restrict__ dsts,
    const bf16_t* __restrict__ W1f, const bf16_t* __restrict__ W2f,
    const float* __restrict__ b1f, const float* __restrict__ b2f,
    bf16_t* __restrict__ mb)
{
    __shared__ __attribute__((aligned(16))) bf16_t w1s[20480];      // 40960 B
    __shared__ __attribute__((aligned(16))) bf16_t w2s[8192];       // 16384 B
    __shared__ __attribute__((aligned(16))) bf16_t hq[4][32 * 36];  //  9216 B

    const int tid = threadIdx.x;
    {
        const uint4* s1 = (const uint4*)W1f;
        uint4* d1 = (uint4*)w1s;
        #pragma unroll
        for (int i = 0; i < 10; i++) d1[tid + i * 256] = s1[tid + i * 256];
        const uint4* s2 = (const uint4*)W2f;
        uint4* d2 = (uint4*)w2s;
        #pragma unroll
        for (int i = 0; i < 4; i++) d2[tid + i * 256] = s2[tid + i * 256];
    }
    __syncthreads();

    const int lane = tid & 63;
    const int wv   = tid >> 6;
    const int l15  = lane & 15;
    const int quad = lane >> 4;

    float b1r[8], b2r[4];
    #pragma unroll
    for (int nt = 0; nt < 8; nt++) b1r[nt] = b1f[nt * 16 + l15];
    #pragma unroll
    for (int nt = 0; nt < 4; nt++) b2r[nt] = b2f[nt * 16 + l15];

    const int WTOT = gridDim.x * 4;

    // idx layout: [0]=src0,[1]=dst0,[2]=src1,[3]=dst1 (rows l15 / 16+l15)
    auto LDIDX = [&](int pp, int* idx) {
        int b = pp * 32;
        idx[0] = srcs[b + l15];       idx[1] = dsts[b + l15];
        idx[2] = srcs[b + 16 + l15];  idx[3] = dsts[b + 16 + l15];
    };
    // af layout: [0..3]=grp0 src lo/hi,dst lo/hi, [4]=grp0 ef,
    //            [5..8]=grp1 src lo/hi,dst lo/hi, [9]=grp1 ef
    auto GATHER = [&](const int* idx, int pp, bf16x8* af) {
        const bf16_t* sp0 = hb + (size_t)idx[0] * 64 + quad * 8;
        const bf16_t* dp0 = hb + (size_t)idx[1] * 64 + quad * 8;
        const bf16_t* sp1 = hb + (size_t)idx[2] * 64 + quad * 8;
        const bf16_t* dp1 = hb + (size_t)idx[3] * 64 + quad * 8;
        af[0] = *(const bf16x8*)sp0;  af[1] = *(const bf16x8*)(sp0 + 32);
        af[2] = *(const bf16x8*)dp0;  af[3] = *(const bf16x8*)(dp0 + 32);
        af[5] = *(const bf16x8*)sp1;  af[6] = *(const bf16x8*)(sp1 + 32);
        af[7] = *(const bf16x8*)dp1;  af[8] = *(const bf16x8*)(dp1 + 32);
        if (quad == 0) {
            int b = pp * 32;
            af[4] = *(const bf16x8*)(efpb + (size_t)(b + l15) * 8);
            af[9] = *(const bf16x8*)(efpb + (size_t)(b + 16 + l15) * 8);
        }
    };
    auto COMPSTORE = [&](const bf16x8* af, int pcur) {
        floatx4 oa0[4], oa1[4];
        #pragma unroll
        for (int nt = 0; nt < 4; nt++) {
            oa0[nt].x=0.f; oa0[nt].y=0.f; oa0[nt].z=0.f; oa0[nt].w=0.f;
            oa1[nt].x=0.f; oa1[nt].y=0.f; oa1[nt].z=0.f; oa1[nt].w=0.f;
        }
        #pragma unroll
        for (int q = 0; q < 4; q++) {
            floatx4 ac0[2], ac1[2];
            #pragma unroll
            for (int nt = 0; nt < 2; nt++) {
                ac0[nt].x=0.f; ac0[nt].y=0.f; ac0[nt].z=0.f; ac0[nt].w=0.f;
                ac1[nt].x=0.f; ac1[nt].y=0.f; ac1[nt].z=0.f; ac1[nt].w=0.f;
            }
            #pragma unroll
            for (int nt = 0; nt < 2; nt++) {
                int gnt = q * 2 + nt;
                #pragma unroll
                for (int ks = 0; ks < 5; ks++) {
                    bf16x8 b = *(const bf16x8*)(w1s + ((gnt * 5 + ks) * 64 + lane) * 8);
                    ac0[nt] = mfma16(af[ks], b, ac0[nt]);
                    ac1[nt] = mfma16(af[5 + ks], b, ac1[nt]);
                }
            }
            #pragma unroll
            for (int nt = 0; nt < 2; nt++) {
                float bb = b1r[q * 2 + nt];
                #pragma unroll
                for (int r = 0; r < 4; r++) {
                    float v0 = fmaxf(ac0[nt][r] + bb, 0.f);
                    float v1 = fmaxf(ac1[nt][r] + bb, 0.f);
                    hq[wv][(quad * 4 + r) * 36 + nt * 16 + l15]      = (bf16_t)v0;
                    hq[wv][(16 + quad * 4 + r) * 36 + nt * 16 + l15] = (bf16_t)v1;
                }
            }
            // same-wave write->read (compiler lgkmcnt)
            bf16x8 hf0 = *(const bf16x8*)(hq[wv] + l15 * 36 + quad * 8);
            bf16x8 hf1 = *(const bf16x8*)(hq[wv] + (16 + l15) * 36 + quad * 8);
            #pragma unroll
            for (int nt = 0; nt < 4; nt++) {
                bf16x8 w2 = *(const bf16x8*)(w2s + ((nt * 4 + q) * 64 + lane) * 8);
                oa0[nt] = mfma16(hf0, w2, oa0[nt]);
                oa1[nt] = mfma16(hf1, w2, oa1[nt]);
            }
        }
        // epilogue: plain bf16 stores of m (+b2), sorted edge order
        int base = pcur * 32;
        #pragma unroll
        for (int nt = 0; nt < 4; nt++) {
            int col = nt * 16 + l15;
            float bb = b2r[nt];
            #pragma unroll
            for (int r = 0; r < 4; r++) {
                int row0 = base + quad * 4 + r;
                int row1 = base + 16 + quad * 4 + r;
                mb[(size_t)row0 * 64 + col] = (bf16_t)(oa0[nt][r] + bb);
                mb[(size_t)row1 * 64 + col] = (bf16_t)(oa1[nt][r] + bb);
            }
        }
    };

    int p = blockIdx.x * 4 + wv;           // current pair index
    int iA[4], iB[4];
    bf16x8 afA[10], afB[10];
    if (quad != 0) {
        #pragma unroll
        for (int q = 0; q < 8; q++) {
            afA[4][q] = (bf16_t)0.f; afA[9][q] = (bf16_t)0.f;
            afB[4][q] = (bf16_t)0.f; afB[9][q] = (bf16_t)0.f;
        }
    }

    // prologue: gather pair-0 into afA; indices for pair-1 into iB
    LDIDX(p, iA);
    GATHER(iA, p, afA);
    int pn = p + WTOT;
    int pp = (pn < NPAIR) ? pn : p;        // clamped, in-bounds
    LDIDX(pp, iB);

    while (true) {
        // phase A: consume afA(pair p); issue gather(iB@pp)->afB; idx 2-ahead->iA
        GATHER(iB, pp, afB);
        {
            int pn2 = pn + WTOT;
            int pq  = (pn2 < NPAIR) ? pn2 : pp;
            LDIDX(pq, iA);
            COMPSTORE(afA, p);
            if (pn >= NPAIR) break;
            p = pn; pn = pn2; pp = pq;
        }
        // phase B: consume afB(pair p); issue gather(iA@pp)->afA; idx 2-ahead->iB
        GATHER(iA, pp, afA);
        {
            int pn2 = pn + WTOT;
            int pq  = (pn2 < NPAIR) ? pn2 : pp;
            LDIDX(pq, iB);
            COMPSTORE(afB, p);
            if (pn >= NPAIR) break;
            p = pn; pn = pn2; pp = pq;
        }
    }
}

// ---------------------------------------------------------------------------
// agg kernel (v19): vectorized CSR gather-sum on the LOGICAL mb layout.
// Lane (quad,l15) loads bf16x4 at mb[e*64 + l15*4]; quads stride rows ->
// 4 rows per load instruction. Cross-quad shfl_xor reduce; quad 0 writes
// one bf16x4 per lane. Untouched.
// ---------------------------------------------------------------------------
__global__ __launch_bounds__(256) void agg_kernel(
    const bf16_t* __restrict__ mb, const int* __restrict__ deg,
    const int* __restrict__ cursor, bf16_t* __restrict__ aggb)
{
    const int node = blockIdx.x * 4 + (threadIdx.x >> 6);
    if (node >= NN) return;
    const int lane = threadIdx.x & 63;
    const int l15  = lane & 15;
    const int quad = lane >> 4;
    int dg  = deg[node];
    int end = cursor[node];
    int st  = end - dg;
    float a0 = 0.f, a1 = 0.f, a2 = 0.f, a3 = 0.f;
    for (int e = st + quad; e < end; e += 4) {
        bf16x4 v = *(const bf16x4*)(mb + (size_t)e * 64 + l15 * 4);
        a0 += (float)v[0]; a1 += (float)v[1]; a2 += (float)v[2]; a3 += (float)v[3];
    }
    a0 += __shfl_xor(a0, 16, 64); a0 += __shfl_xor(a0, 32, 64);
    a1 += __shfl_xor(a1, 16, 64); a1 += __shfl_xor(a1, 32, 64);
    a2 += __shfl_xor(a2, 16, 64); a2 += __shfl_xor(a2, 32, 64);
    a3 += __shfl_xor(a3, 16, 64); a3 += __shfl_xor(a3, 32, 64);
    if (quad == 0) {
        bf16x4 o;
        o[0] = (bf16_t)a0; o[1] = (bf16_t)a1; o[2] = (bf16_t)a2; o[3] = (bf16_t)a3;
        *(bf16x4*)(aggb + (size_t)node * 64 + l15 * 4) = o;
    }
}

// ---------------------------------------------------------------------------
// GRU (MFMA): 64 nodes/block, 16/wave. agg input bf16 (logical layout).
// LAST=0: emits fp32 h + bf16 hb. LAST=1: fused readout MLP.
// ---------------------------------------------------------------------------
template<int LAST>
__global__ __launch_bounds__(256) void gru_kernel(
    const bf16_t* __restrict__ aggb, const float* __restrict__ h_in,
    float* __restrict__ h_out, bf16_t* __restrict__ hb_out,
    const bf16_t* __restrict__ Wxt, const bf16_t* __restrict__ Wht,
    const float* __restrict__ bg,
    const bf16_t* __restrict__ Wr1f, const float* __restrict__ br1,
    const float* __restrict__ Wr2, const float* __restrict__ br2,
    float* __restrict__ out)
{
    __shared__ __attribute__((aligned(16))) float  shd[64 * 68];    // 17408 B
    __shared__ __attribute__((aligned(16))) bf16_t hb2[4][16 * 72]; //  9216 B
    const int tid = threadIdx.x;
    const int n0  = blockIdx.x * 64;

    for (int idx = tid; idx < 64 * 16; idx += 256) {
        int i = idx >> 4, c = (idx & 15) * 4;
        int n = n0 + i; if (n >= NN) n = NN - 1;
        *(float4*)&shd[i * 68 + c] = *(const float4*)(h_in + (size_t)n * 64 + c);
    }
    __syncthreads();

    const int lane = tid & 63;
    const int wv   = tid >> 6;
    const int l15  = lane & 15;
    const int quad = lane >> 4;
    const int rowA = wv * 16 + l15;
    int nA = n0 + rowA; if (nA >= NN) nA = NN - 1;

    bf16x8 ax[2], ah[2];
    ax[0] = *(const bf16x8*)(aggb + (size_t)nA * 64 + quad * 8);
    ax[1] = *(const bf16x8*)(aggb + (size_t)nA * 64 + quad * 8 + 32);
    {
        const float* hp = shd + rowA * 68 + quad * 8;
        ah[0] = cvt8(hp);
        ah[1] = cvt8(hp + 32);
    }

    floatx4 az[4], ar[4], axh[4], ahh[4];
    #pragma unroll
    for (int nt = 0; nt < 4; nt++) {
        az[nt].x=0.f; az[nt].y=0.f; az[nt].z=0.f; az[nt].w=0.f;
        ar[nt].x=0.f; ar[nt].y=0.f; ar[nt].z=0.f; ar[nt].w=0.f;
        axh[nt].x=0.f; axh[nt].y=0.f; axh[nt].z=0.f; axh[nt].w=0.f;
        ahh[nt].x=0.f; ahh[nt].y=0.f; ahh[nt].z=0.f; ahh[nt].w=0.f;
    }
    #pragma unroll
    for (int nt = 0; nt < 4; nt++) {
        const bf16_t* bx_z = Wxt + (nt * 16 + l15) * 64 + quad * 8;
        const bf16_t* bh_z = Wht + (nt * 16 + l15) * 64 + quad * 8;
        const bf16_t* bx_r = bx_z + 64 * 64;
        const bf16_t* bh_r = bh_z + 64 * 64;
        const bf16_t* bx_h = bx_z + 128 * 64;
        const bf16_t* bh_h = bh_z + 128 * 64;
        az[nt]  = mfma16(ax[0], *(const bf16x8*)bx_z,        az[nt]);
        az[nt]  = mfma16(ax[1], *(const bf16x8*)(bx_z + 32), az[nt]);
        az[nt]  = mfma16(ah[0], *(const bf16x8*)bh_z,        az[nt]);
        az[nt]  = mfma16(ah[1], *(const bf16x8*)(bh_z + 32), az[nt]);
        ar[nt]  = mfma16(ax[0], *(const bf16x8*)bx_r,        ar[nt]);
        ar[nt]  = mfma16(ax[1], *(const bf16x8*)(bx_r + 32), ar[nt]);
        ar[nt]  = mfma16(ah[0], *(const bf16x8*)bh_r,        ar[nt]);
        ar[nt]  = mfma16(ah[1], *(const bf16x8*)(bh_r + 32), ar[nt]);
        axh[nt] = mfma16(ax[0], *(const bf16x8*)bx_h,        axh[nt]);
        axh[nt] = mfma16(ax[1], *(const bf16x8*)(bx_h + 32), axh[nt]);
        ahh[nt] = mfma16(ah[0], *(const bf16x8*)bh_h,        ahh[nt]);
        ahh[nt] = mfma16(ah[1], *(const bf16x8*)(bh_h + 32), ahh[nt]);
    }

    #pragma unroll
    for (int nt = 0; nt < 4; nt++) {
        int j = nt * 16 + l15;
        float bz = bg[j], brr = bg[64 + j], bh = bg[128 + j];
        #pragma unroll
        for (int r = 0; r < 4; r++) {
            int lrow = wv * 16 + quad * 4 + r;
            int n = n0 + lrow;
            float z  = sigm_f(az[nt][r] + bz);
            float rr = sigm_f(ar[nt][r] + brr);
            float hc = tanh_f(axh[nt][r] + bh + rr * ahh[nt][r]);
            float hold = shd[lrow * 68 + j];
            float hnew = z * hold + (1.f - z) * hc;
            if (LAST) {
                hb2[wv][(quad * 4 + r) * 72 + j] = (bf16_t)hnew;
            } else if (n < NN) {
                h_out[(size_t)n * 64 + j]  = hnew;
                hb_out[(size_t)n * 64 + j] = (bf16_t)hnew;
            }
        }
    }

    if (LAST) {
        bf16x8 a0 = *(const bf16x8*)(hb2[wv] + l15 * 72 + quad * 8);
        bf16x8 a1 = *(const bf16x8*)(hb2[wv] + l15 * 72 + quad * 8 + 32);
        floatx4 accR[8];
        #pragma unroll
        for (int nt = 0; nt < 8; nt++) { accR[nt].x=0.f; accR[nt].y=0.f; accR[nt].z=0.f; accR[nt].w=0.f; }
        #pragma unroll
        for (int nt = 0; nt < 8; nt++) {
            bf16x8 b0 = *(const bf16x8*)(Wr1f + ((nt * 2 + 0) * 64 + lane) * 8);
            bf16x8 b1 = *(const bf16x8*)(Wr1f + ((nt * 2 + 1) * 64 + lane) * 8);
            accR[nt] = mfma16(a0, b0, accR[nt]);
            accR[nt] = mfma16(a1, b1, accR[nt]);
        }
        float br1r[8], wr2r[8];
        #pragma unroll
        for (int nt = 0; nt < 8; nt++) {
            br1r[nt] = br1[nt * 16 + l15];
            wr2r[nt] = Wr2[nt * 16 + l15];
        }
        float br2v = br2[0];
        #pragma unroll
        for (int r = 0; r < 4; r++) {
            float p = 0.f;
            #pragma unroll
            for (int nt = 0; nt < 8; nt++)
                p += fmaxf(accR[nt][r] + br1r[nt], 0.f) * wr2r[nt];
            p += __shfl_xor(p, 1, 64);
            p += __shfl_xor(p, 2, 64);
            p += __shfl_xor(p, 4, 64);
            p += __shfl_xor(p, 8, 64);
            if (l15 == 0) {
                int n = n0 + wv * 16 + quad * 4 + r;
                if (n < NN) out[n] = p + br2v;
            }
        }
    }
}

// ---------------------------------------------------------------------------
extern "C" void kernel_launch(void* const* d_in, const int* in_sizes, int n_in,
                              void* d_out, int out_size, void* d_ws, size_t ws_size,
                              hipStream_t stream)
{
    const float* nf  = (const float*)d_in[0];
    const float* ef  = (const float*)d_in[1];
    const int* esrc  = (const int*)d_in[2];
    const int* edst  = (const int*)d_in[3];
    const float* Wm1 = (const float*)d_in[4];
    const float* bm1 = (const float*)d_in[5];
    const float* Wm2 = (const float*)d_in[6];
    const float* bm2 = (const float*)d_in[7];
    const float* Wx  = (const float*)d_in[8];
    const float* Wh  = (const float*)d_in[9];
    const float* bg  = (const float*)d_in[10];
    const float* Wr1 = (const float*)d_in[11];
    const float* br1 = (const float*)d_in[12];
    const float* Wr2 = (const float*)d_in[13];
    const float* br2 = (const float*)d_in[14];

    char* ws = (char*)d_ws;
    float*  hbuf   = (float*)(ws);                   // 12,800,000
    bf16_t* hb     = (bf16_t*)(ws + 12800000);       // 6,400,000
    bf16_t* W1f    = (bf16_t*)(ws + 19200000);       // 40,960
    bf16_t* W2f    = (bf16_t*)(ws + 19240960);       // 16,384
    bf16_t* Wxt    = (bf16_t*)(ws + 19257344);       // 24,576
    bf16_t* Wht    = (bf16_t*)(ws + 19281920);       // 24,576
    bf16_t* Wr1f   = (bf16_t*)(ws + 19306496);       // 16,384
    int*    srcs   = (int*)(ws + 19322880);          // 1,600,000
    int*    dsts   = (int*)(ws + 20922880);          // 1,600,000
    bf16_t* efpb   = (bf16_t*)(ws + 22522880);       // 6,400,000
    int*    deg    = (int*)(ws + 28922880);          // 200,704
    int*    cursor = (int*)(ws + 29123584);          // 200,704
    int*    chunkS = (int*)(ws + 29324288);          // 1,024
    int*    chunkO = (int*)(ws + 29325312);          // 1,024 (unused now)
    bf16_t* aggb   = (bf16_t*)(ws + 29326336);       // 6,400,000
    bf16_t* mb     = (bf16_t*)(ws + 35726336);       // 51,200,000
    (void)chunkO;

    // deg must be zero before prep's fused histogram
    hipMemsetAsync(deg, 0, (size_t)NPAD * 4, stream);
    prep_kernel<<<4928, 256, 0, stream>>>(nf, Wm1, Wm2, Wx, Wh, Wr1, edst, deg,
                                          hb, W1f, W2f, Wxt, Wht, Wr1f);

    scanA_kernel<<<NCH, 256, 0, stream>>>(deg, chunkS);
    scanC_kernel<<<NCH, 256, 0, stream>>>(deg, chunkS, cursor);
    scatter_kernel<<<(NE + 255) / 256, 256, 0, stream>>>(esrc, edst, ef, cursor,
                                                         srcs, dsts, efpb);

    // step 0
    edge_kernel<<<1024, 256, 0, stream>>>(hb, efpb, srcs, dsts,
                                          W1f, W2f, bm1, bm2, mb);
    agg_kernel<<<(NN + 3) / 4, 256, 0, stream>>>(mb, deg, cursor, aggb);
    gru_kernel<0><<<(NN + 63) / 64, 256, 0, stream>>>(
        aggb, nf, hbuf, hb, Wxt, Wht, bg, Wr1f, br1, Wr2, br2, (float*)d_out);
    // step 1
    edge_kernel<<<1024, 256, 0, stream>>>(hb, efpb, srcs, dsts,
                                          W1f, W2f, bm1, bm2, mb);
    agg_kernel<<<(NN + 3) / 4, 256, 0, stream>>>(mb, deg, cursor, aggb);
    gru_kernel<1><<<(NN + 63) / 64, 256, 0, stream>>>(
        aggb, hbuf, nullptr, nullptr, Wxt, Wht, bg, Wr1f, br1, Wr2, br2,
        (float*)d_out);
}

// Round 9
// 306.491 us; speedup vs baseline: 1.0351x; 1.0163x over previous
//
#include <hip/hip_runtime.h>
#include <hip/hip_bf16.h>

#define NN 50000
#define NE 400000
#define NPAIR 12500        // NE/32: 32 sorted edges per wave-iteration
#define NCH 196            // ceil(50176/256) scan chunks
#define NPAD 50176         // NCH*256

typedef __bf16 bf16_t;
typedef __bf16 bf16x2 __attribute__((ext_vector_type(2)));
typedef __bf16 bf16x4 __attribute__((ext_vector_type(4)));
typedef __bf16 bf16x8 __attribute__((ext_vector_type(8)));
typedef float  floatx4 __attribute__((ext_vector_type(4)));

static __device__ __forceinline__ floatx4 mfma16(bf16x8 a, bf16x8 b, floatx4 c) {
    return __builtin_amdgcn_mfma_f32_16x16x32_bf16(a, b, c, 0, 0, 0);
}
static __device__ __forceinline__ float sigm_f(float x) {
    return 1.f / (1.f + __expf(-x));
}
static __device__ __forceinline__ float tanh_f(float x) {
    return 1.f - 2.f / (__expf(2.f * x) + 1.f);
}
static __device__ __forceinline__ bf16x8 cvt8(const float* sp) {
    float4 f0 = *(const float4*)sp;
    float4 f1 = *(const float4*)(sp + 4);
    bf16x8 v;
    v[0] = (bf16_t)f0.x; v[1] = (bf16_t)f0.y; v[2] = (bf16_t)f0.z; v[3] = (bf16_t)f0.w;
    v[4] = (bf16_t)f1.x; v[5] = (bf16_t)f1.y; v[6] = (bf16_t)f1.z; v[7] = (bf16_t)f1.w;
    return v;
}

// ---------------------------------------------------------------------------
// prep (fused): bf16 h copy + weight transforms + degree histogram (tail).
// W2f carries the hq k-permutation sigma(local) = (local>>1)+(local&1)*16 so
// the edge kernel's msg2 A-operand reads contiguous b128 from the packed hq
// layout (phys col p = 2*l15+nt). GEMM k-order is free when A and B agree —
// numerically verified in the v13/v14/v15 runs (all passed, absmax 0.0015).
// ---------------------------------------------------------------------------
__global__ __launch_bounds__(256) void prep_kernel(
    const float* __restrict__ nf,
    const float* __restrict__ Wm1, const float* __restrict__ Wm2,
    const float* __restrict__ Wx,  const float* __restrict__ Wh,
    const float* __restrict__ Wr1,
    const int* __restrict__ edst, int* __restrict__ deg,
    bf16_t* __restrict__ hb,
    bf16_t* __restrict__ W1f, bf16_t* __restrict__ W2f,
    bf16_t* __restrict__ Wxt, bf16_t* __restrict__ Wht,
    bf16_t* __restrict__ Wr1f)
{
    int u = blockIdx.x * 256 + threadIdx.x;
    if (u < 800000) {          // hb: 4 elems per thread
        float4 v = *(const float4*)(nf + (size_t)u * 4);
        bf16x4 o;
        o[0] = (bf16_t)v.x; o[1] = (bf16_t)v.y; o[2] = (bf16_t)v.z; o[3] = (bf16_t)v.w;
        *(bf16x4*)(hb + (size_t)u * 4) = o;
        return;
    }
    u -= 800000;
    if (u < 20480) {
        int j = u & 7, l = (u >> 3) & 63, rem = u >> 9;   // rem 0..39
        int ks = rem % 5, nt = rem / 5;
        int n = nt * 16 + (l & 15);
        int k = ks * 32 + (l >> 4) * 8 + j;
        W1f[u] = (k < 136) ? (bf16_t)Wm1[k * 128 + n] : (bf16_t)0.f;
        return;
    }
    u -= 20480;
    if (u < 8192) {
        int j = u & 7, l = (u >> 3) & 63, rem = u >> 9;   // rem 0..15
        int kg = rem & 3, nt = rem >> 2;
        int n = nt * 16 + (l & 15);
        int local = (l >> 4) * 8 + j;
        int k = kg * 32 + (local >> 1) + (local & 1) * 16;  // sigma perm
        W2f[u] = (bf16_t)Wm2[k * 64 + n];
        return;
    }
    u -= 8192;
    if (u < 12288) {
        int n = u >> 6, k = u & 63;
        Wxt[u] = (bf16_t)Wx[k * 192 + n];
        return;
    }
    u -= 12288;
    if (u < 12288) {
        int n = u >> 6, k = u & 63;
        Wht[u] = (bf16_t)Wh[k * 192 + n];
        return;
    }
    u -= 12288;
    if (u < 8192) {            // Wr1f
        int j = u & 7, l = (u >> 3) & 63, rem = u >> 9;   // rem 0..15
        int kg = rem & 1, nt = rem >> 1;
        int n = nt * 16 + (l & 15);
        int k = kg * 32 + (l >> 4) * 8 + j;
        Wr1f[u] = (bf16_t)Wr1[k * 128 + n];
        return;
    }
    u -= 8192;
    if (u < NE) atomicAdd(&deg[edst[u]], 1);   // fused histogram
}

// ---------------------------------------------------------------------------
// CSR build: scanA -> scanC (self-prefix) -> scatter (v20 structure).
// ---------------------------------------------------------------------------
__global__ __launch_bounds__(256) void scanA_kernel(
    const int* __restrict__ deg, int* __restrict__ chunkSums)
{
    __shared__ int s[256];
    int i = blockIdx.x * 256 + threadIdx.x;
    s[threadIdx.x] = deg[i];
    __syncthreads();
    for (int st = 128; st >= 1; st >>= 1) {
        if (threadIdx.x < st) s[threadIdx.x] += s[threadIdx.x + st];
        __syncthreads();
    }
    if (threadIdx.x == 0) chunkSums[blockIdx.x] = s[0];
}

__global__ __launch_bounds__(256) void scanC_kernel(
    const int* __restrict__ deg, const int* __restrict__ chunkSums,
    int* __restrict__ cursor)
{
    __shared__ int s[256];
    __shared__ int baseS;
    const int t   = threadIdx.x;
    const int bid = blockIdx.x;

    // block-wide sum of chunkSums[0..bid-1]  (bid <= 195 < 256)
    s[t] = (t < bid) ? chunkSums[t] : 0;
    __syncthreads();
    for (int st = 128; st >= 1; st >>= 1) {
        if (t < st) s[t] += s[t + st];
        __syncthreads();
    }
    if (t == 0) baseS = s[0];
    __syncthreads();
    const int base = baseS;

    // local exclusive scan of this chunk's degrees
    int i = bid * 256 + t;
    int v = deg[i];
    __syncthreads();           // all reads of s in reduce done before reuse
    s[t] = v;
    __syncthreads();
    for (int st = 1; st < 256; st <<= 1) {
        int add = (t >= st) ? s[t - st] : 0;
        __syncthreads();
        s[t] += add;
        __syncthreads();
    }
    cursor[i] = base + s[t] - v;   // exclusive
}

__global__ __launch_bounds__(256) void scatter_kernel(
    const int* __restrict__ esrc, const int* __restrict__ edst,
    const float* __restrict__ ef,
    int* __restrict__ cursor, int* __restrict__ srcs, int* __restrict__ dsts,
    bf16_t* __restrict__ efpb)
{
    int e = blockIdx.x * 256 + threadIdx.x;
    if (e >= NE) return;
    int d = edst[e];
    int p = atomicAdd(&cursor[d], 1);    // cursor ends at row-end offsets
    srcs[p] = esrc[e];
    dsts[p] = d;
    float4 a = *(const float4*)(ef + (size_t)e * 8);
    float4 b = *(const float4*)(ef + (size_t)e * 8 + 4);
    bf16x8 v;
    v[0] = (bf16_t)a.x; v[1] = (bf16_t)a.y; v[2] = (bf16_t)a.z; v[3] = (bf16_t)a.w;
    v[4] = (bf16_t)b.x; v[5] = (bf16_t)b.y; v[6] = (bf16_t)b.z; v[7] = (bf16_t)b.w;
    *(bf16x8*)(efpb + (size_t)p * 8) = v;
}

// ---------------------------------------------------------------------------
// edge kernel v21: v20 (2-deep pipeline, scalar logical mb stores) + ONE
// change: hq written packed (phys col p = 2*l15+nt) as ds_write_b32 — 64 b16
// -> 32 b32 LDS writes/iter, floor 1139 -> 954 cy. W2f carries the matching
// sigma k-perm; the hq b128 READ path is unchanged. Spill theory (r8): the
// v13-15 FETCH/WRITE amplification tracked __launch_bounds__ VGPR caps
// (scratch spill through HBM), NOT this layout — so this build stays
// UNCAPPED __launch_bounds__(256). Tripwire: FETCH>40MB here convicts
// packed-hq intrinsically and it gets permanently reverted.
// ---------------------------------------------------------------------------
__global__ __launch_bounds__(256) void edge_kernel(
    const bf16_t* __restrict__ hb, const bf16_t* __restrict__ efpb,
    const int* __restrict__ srcs, const int* __restrict__ dsts,
    const bf16_t* __restrict__ W1f, const bf16_t* __restrict__ W2f,
    const float* __restrict__ b1f, const float* __restrict__ b2f,
    bf16_t* __restrict__ mb)
{
    __shared__ __attribute__((aligned(16))) bf16_t w1s[20480];      // 40960 B
    __shared__ __attribute__((aligned(16))) bf16_t w2s[8192];       // 16384 B
    __shared__ __attribute__((aligned(16))) bf16_t hq[4][32 * 36];  //  9216 B

    const int tid = threadIdx.x;
    {
        const uint4* s1 = (const uint4*)W1f;
        uint4* d1 = (uint4*)w1s;
        #pragma unroll
        for (int i = 0; i < 10; i++) d1[tid + i * 256] = s1[tid + i * 256];
        const uint4* s2 = (const uint4*)W2f;
        uint4* d2 = (uint4*)w2s;
        #pragma unroll
        for (int i = 0; i < 4; i++) d2[tid + i * 256] = s2[tid + i * 256];
    }
    __syncthreads();

    const int lane = tid & 63;
    const int wv   = tid >> 6;
    const int l15  = lane & 15;
    const int quad = lane >> 4;

    float b1r[8], b2r[4];
    #pragma unroll
    for (int nt = 0; nt < 8; nt++) b1r[nt] = b1f[nt * 16 + l15];
    #pragma unroll
    for (int nt = 0; nt < 4; nt++) b2r[nt] = b2f[nt * 16 + l15];

    const int WTOT = gridDim.x * 4;

    // idx layout: [0]=src0,[1]=dst0,[2]=src1,[3]=dst1 (rows l15 / 16+l15)
    auto LDIDX = [&](int pp, int* idx) {
        int b = pp * 32;
        idx[0] = srcs[b + l15];       idx[1] = dsts[b + l15];
        idx[2] = srcs[b + 16 + l15];  idx[3] = dsts[b + 16 + l15];
    };
    // af layout: [0..3]=grp0 src lo/hi,dst lo/hi, [4]=grp0 ef,
    //            [5..8]=grp1 src lo/hi,dst lo/hi, [9]=grp1 ef
    auto GATHER = [&](const int* idx, int pp, bf16x8* af) {
        const bf16_t* sp0 = hb + (size_t)idx[0] * 64 + quad * 8;
        const bf16_t* dp0 = hb + (size_t)idx[1] * 64 + quad * 8;
        const bf16_t* sp1 = hb + (size_t)idx[2] * 64 + quad * 8;
        const bf16_t* dp1 = hb + (size_t)idx[3] * 64 + quad * 8;
        af[0] = *(const bf16x8*)sp0;  af[1] = *(const bf16x8*)(sp0 + 32);
        af[2] = *(const bf16x8*)dp0;  af[3] = *(const bf16x8*)(dp0 + 32);
        af[5] = *(const bf16x8*)sp1;  af[6] = *(const bf16x8*)(sp1 + 32);
        af[7] = *(const bf16x8*)dp1;  af[8] = *(const bf16x8*)(dp1 + 32);
        if (quad == 0) {
            int b = pp * 32;
            af[4] = *(const bf16x8*)(efpb + (size_t)(b + l15) * 8);
            af[9] = *(const bf16x8*)(efpb + (size_t)(b + 16 + l15) * 8);
        }
    };
    auto COMPSTORE = [&](const bf16x8* af, int pcur) {
        floatx4 oa0[4], oa1[4];
        #pragma unroll
        for (int nt = 0; nt < 4; nt++) {
            oa0[nt].x=0.f; oa0[nt].y=0.f; oa0[nt].z=0.f; oa0[nt].w=0.f;
            oa1[nt].x=0.f; oa1[nt].y=0.f; oa1[nt].z=0.f; oa1[nt].w=0.f;
        }
        #pragma unroll
        for (int q = 0; q < 4; q++) {
            floatx4 ac0[2], ac1[2];
            #pragma unroll
            for (int nt = 0; nt < 2; nt++) {
                ac0[nt].x=0.f; ac0[nt].y=0.f; ac0[nt].z=0.f; ac0[nt].w=0.f;
                ac1[nt].x=0.f; ac1[nt].y=0.f; ac1[nt].z=0.f; ac1[nt].w=0.f;
            }
            #pragma unroll
            for (int nt = 0; nt < 2; nt++) {
                int gnt = q * 2 + nt;
                #pragma unroll
                for (int ks = 0; ks < 5; ks++) {
                    bf16x8 b = *(const bf16x8*)(w1s + ((gnt * 5 + ks) * 64 + lane) * 8);
                    ac0[nt] = mfma16(af[ks], b, ac0[nt]);
                    ac1[nt] = mfma16(af[5 + ks], b, ac1[nt]);
                }
            }
            // relu+bias, pack 2 nt-cols -> one ds_write_b32 (phys col 2*l15+nt)
            {
                float bb0 = b1r[q * 2 + 0], bb1 = b1r[q * 2 + 1];
                #pragma unroll
                for (int r = 0; r < 4; r++) {
                    float v00 = fmaxf(ac0[0][r] + bb0, 0.f);
                    float v01 = fmaxf(ac0[1][r] + bb1, 0.f);
                    bf16x2 t0; t0[0] = (bf16_t)v00; t0[1] = (bf16_t)v01;
                    *(bf16x2*)(hq[wv] + (quad * 4 + r) * 36 + l15 * 2) = t0;
                    float v10 = fmaxf(ac1[0][r] + bb0, 0.f);
                    float v11 = fmaxf(ac1[1][r] + bb1, 0.f);
                    bf16x2 t1; t1[0] = (bf16_t)v10; t1[1] = (bf16_t)v11;
                    *(bf16x2*)(hq[wv] + (16 + quad * 4 + r) * 36 + l15 * 2) = t1;
                }
            }
            // same-wave write->read (compiler lgkmcnt); read path unchanged
            bf16x8 hf0 = *(const bf16x8*)(hq[wv] + l15 * 36 + quad * 8);
            bf16x8 hf1 = *(const bf16x8*)(hq[wv] + (16 + l15) * 36 + quad * 8);
            #pragma unroll
            for (int nt = 0; nt < 4; nt++) {
                bf16x8 w2 = *(const bf16x8*)(w2s + ((nt * 4 + q) * 64 + lane) * 8);
                oa0[nt] = mfma16(hf0, w2, oa0[nt]);
                oa1[nt] = mfma16(hf1, w2, oa1[nt]);
            }
        }
        // epilogue: plain bf16 stores of m (+b2), sorted edge order
        int base = pcur * 32;
        #pragma unroll
        for (int nt = 0; nt < 4; nt++) {
            int col = nt * 16 + l15;
            float bb = b2r[nt];
            #pragma unroll
            for (int r = 0; r < 4; r++) {
                int row0 = base + quad * 4 + r;
                int row1 = base + 16 + quad * 4 + r;
                mb[(size_t)row0 * 64 + col] = (bf16_t)(oa0[nt][r] + bb);
                mb[(size_t)row1 * 64 + col] = (bf16_t)(oa1[nt][r] + bb);
            }
        }
    };

    int p = blockIdx.x * 4 + wv;           // current pair index
    int iA[4], iB[4];
    bf16x8 afA[10], afB[10];
    if (quad != 0) {
        #pragma unroll
        for (int q = 0; q < 8; q++) {
            afA[4][q] = (bf16_t)0.f; afA[9][q] = (bf16_t)0.f;
            afB[4][q] = (bf16_t)0.f; afB[9][q] = (bf16_t)0.f;
        }
    }

    // prologue: gather pair-0 into afA; indices for pair-1 into iB
    LDIDX(p, iA);
    GATHER(iA, p, afA);
    int pn = p + WTOT;
    int pp = (pn < NPAIR) ? pn : p;        // clamped, in-bounds
    LDIDX(pp, iB);

    while (true) {
        // phase A: consume afA(pair p); issue gather(iB@pp)->afB; idx 2-ahead->iA
        GATHER(iB, pp, afB);
        {
            int pn2 = pn + WTOT;
            int pq  = (pn2 < NPAIR) ? pn2 : pp;
            LDIDX(pq, iA);
            COMPSTORE(afA, p);
            if (pn >= NPAIR) break;
            p = pn; pn = pn2; pp = pq;
        }
        // phase B: consume afB(pair p); issue gather(iA@pp)->afA; idx 2-ahead->iB
        GATHER(iA, pp, afA);
        {
            int pn2 = pn + WTOT;
            int pq  = (pn2 < NPAIR) ? pn2 : pp;
            LDIDX(pq, iB);
            COMPSTORE(afB, p);
            if (pn >= NPAIR) break;
            p = pn; pn = pn2; pp = pq;
        }
    }
}

// ---------------------------------------------------------------------------
// agg kernel (v19/v20): vectorized CSR gather-sum on the LOGICAL mb layout.
// ---------------------------------------------------------------------------
__global__ __launch_bounds__(256) void agg_kernel(
    const bf16_t* __restrict__ mb, const int* __restrict__ deg,
    const int* __restrict__ cursor, bf16_t* __restrict__ aggb)
{
    const int node = blockIdx.x * 4 + (threadIdx.x >> 6);
    if (node >= NN) return;
    const int lane = threadIdx.x & 63;
    const int l15  = lane & 15;
    const int quad = lane >> 4;
    int dg  = deg[node];
    int end = cursor[node];
    int st  = end - dg;
    float a0 = 0.f, a1 = 0.f, a2 = 0.f, a3 = 0.f;
    for (int e = st + quad; e < end; e += 4) {
        bf16x4 v = *(const bf16x4*)(mb + (size_t)e * 64 + l15 * 4);
        a0 += (float)v[0]; a1 += (float)v[1]; a2 += (float)v[2]; a3 += (float)v[3];
    }
    a0 += __shfl_xor(a0, 16, 64); a0 += __shfl_xor(a0, 32, 64);
    a1 += __shfl_xor(a1, 16, 64); a1 += __shfl_xor(a1, 32, 64);
    a2 += __shfl_xor(a2, 16, 64); a2 += __shfl_xor(a2, 32, 64);
    a3 += __shfl_xor(a3, 16, 64); a3 += __shfl_xor(a3, 32, 64);
    if (quad == 0) {
        bf16x4 o;
        o[0] = (bf16_t)a0; o[1] = (bf16_t)a1; o[2] = (bf16_t)a2; o[3] = (bf16_t)a3;
        *(bf16x4*)(aggb + (size_t)node * 64 + l15 * 4) = o;
    }
}

// ---------------------------------------------------------------------------
// GRU (MFMA): 64 nodes/block, 16/wave. agg input bf16 (logical layout).
// LAST=0: emits fp32 h + bf16 hb. LAST=1: fused readout MLP.
// ---------------------------------------------------------------------------
template<int LAST>
__global__ __launch_bounds__(256) void gru_kernel(
    const bf16_t* __restrict__ aggb, const float* __restrict__ h_in,
    float* __restrict__ h_out, bf16_t* __restrict__ hb_out,
    const bf16_t* __restrict__ Wxt, const bf16_t* __restrict__ Wht,
    const float* __restrict__ bg,
    const bf16_t* __restrict__ Wr1f, const float* __restrict__ br1,
    const float* __restrict__ Wr2, const float* __restrict__ br2,
    float* __restrict__ out)
{
    __shared__ __attribute__((aligned(16))) float  shd[64 * 68];    // 17408 B
    __shared__ __attribute__((aligned(16))) bf16_t hb2[4][16 * 72]; //  9216 B
    const int tid = threadIdx.x;
    const int n0  = blockIdx.x * 64;

    for (int idx = tid; idx < 64 * 16; idx += 256) {
        int i = idx >> 4, c = (idx & 15) * 4;
        int n = n0 + i; if (n >= NN) n = NN - 1;
        *(float4*)&shd[i * 68 + c] = *(const float4*)(h_in + (size_t)n * 64 + c);
    }
    __syncthreads();

    const int lane = tid & 63;
    const int wv   = tid >> 6;
    const int l15  = lane & 15;
    const int quad = lane >> 4;
    const int rowA = wv * 16 + l15;
    int nA = n0 + rowA; if (nA >= NN) nA = NN - 1;

    bf16x8 ax[2], ah[2];
    ax[0] = *(const bf16x8*)(aggb + (size_t)nA * 64 + quad * 8);
    ax[1] = *(const bf16x8*)(aggb + (size_t)nA * 64 + quad * 8 + 32);
    {
        const float* hp = shd + rowA * 68 + quad * 8;
        ah[0] = cvt8(hp);
        ah[1] = cvt8(hp + 32);
    }

    floatx4 az[4], ar[4], axh[4], ahh[4];
    #pragma unroll
    for (int nt = 0; nt < 4; nt++) {
        az[nt].x=0.f; az[nt].y=0.f; az[nt].z=0.f; az[nt].w=0.f;
        ar[nt].x=0.f; ar[nt].y=0.f; ar[nt].z=0.f; ar[nt].w=0.f;
        axh[nt].x=0.f; axh[nt].y=0.f; axh[nt].z=0.f; axh[nt].w=0.f;
        ahh[nt].x=0.f; ahh[nt].y=0.f; ahh[nt].z=0.f; ahh[nt].w=0.f;
    }
    #pragma unroll
    for (int nt = 0; nt < 4; nt++) {
        const bf16_t* bx_z = Wxt + (nt * 16 + l15) * 64 + quad * 8;
        const bf16_t* bh_z = Wht + (nt * 16 + l15) * 64 + quad * 8;
        const bf16_t* bx_r = bx_z + 64 * 64;
        const bf16_t* bh_r = bh_z + 64 * 64;
        const bf16_t* bx_h = bx_z + 128 * 64;
        const bf16_t* bh_h = bh_z + 128 * 64;
        az[nt]  = mfma16(ax[0], *(const bf16x8*)bx_z,        az[nt]);
        az[nt]  = mfma16(ax[1], *(const bf16x8*)(bx_z + 32), az[nt]);
        az[nt]  = mfma16(ah[0], *(const bf16x8*)bh_z,        az[nt]);
        az[nt]  = mfma16(ah[1], *(const bf16x8*)(bh_z + 32), az[nt]);
        ar[nt]  = mfma16(ax[0], *(const bf16x8*)bx_r,        ar[nt]);
        ar[nt]  = mfma16(ax[1], *(const bf16x8*)(bx_r + 32), ar[nt]);
        ar[nt]  = mfma16(ah[0], *(const bf16x8*)bh_r,        ar[nt]);
        ar[nt]  = mfma16(ah[1], *(const bf16x8*)(bh_r + 32), ar[nt]);
        axh[nt] = mfma16(ax[0], *(const bf16x8*)bx_h,        axh[nt]);
        axh[nt] = mfma16(ax[1], *(const bf16x8*)(bx_h + 32), axh[nt]);
        ahh[nt] = mfma16(ah[0], *(const bf16x8*)bh_h,        ahh[nt]);
        ahh[nt] = mfma16(ah[1], *(const bf16x8*)(bh_h + 32), ahh[nt]);
    }

    #pragma unroll
    for (int nt = 0; nt < 4; nt++) {
        int j = nt * 16 + l15;
        float bz = bg[j], brr = bg[64 + j], bh = bg[128 + j];
        #pragma unroll
        for (int r = 0; r < 4; r++) {
            int lrow = wv * 16 + quad * 4 + r;
            int n = n0 + lrow;
            float z  = sigm_f(az[nt][r] + bz);
            float rr = sigm_f(ar[nt][r] + brr);
            float hc = tanh_f(axh[nt][r] + bh + rr * ahh[nt][r]);
            float hold = shd[lrow * 68 + j];
            float hnew = z * hold + (1.f - z) * hc;
            if (LAST) {
                hb2[wv][(quad * 4 + r) * 72 + j] = (bf16_t)hnew;
            } else if (n < NN) {
                h_out[(size_t)n * 64 + j]  = hnew;
                hb_out[(size_t)n * 64 + j] = (bf16_t)hnew;
            }
        }
    }

    if (LAST) {
        bf16x8 a0 = *(const bf16x8*)(hb2[wv] + l15 * 72 + quad * 8);
        bf16x8 a1 = *(const bf16x8*)(hb2[wv] + l15 * 72 + quad * 8 + 32);
        floatx4 accR[8];
        #pragma unroll
        for (int nt = 0; nt < 8; nt++) { accR[nt].x=0.f; accR[nt].y=0.f; accR[nt].z=0.f; accR[nt].w=0.f; }
        #pragma unroll
        for (int nt = 0; nt < 8; nt++) {
            bf16x8 b0 = *(const bf16x8*)(Wr1f + ((nt * 2 + 0) * 64 + lane) * 8);
            bf16x8 b1 = *(const bf16x8*)(Wr1f + ((nt * 2 + 1) * 64 + lane) * 8);
            accR[nt] = mfma16(a0, b0, accR[nt]);
            accR[nt] = mfma16(a1, b1, accR[nt]);
        }
        float br1r[8], wr2r[8];
        #pragma unroll
        for (int nt = 0; nt < 8; nt++) {
            br1r[nt] = br1[nt * 16 + l15];
            wr2r[nt] = Wr2[nt * 16 + l15];
        }
        float br2v = br2[0];
        #pragma unroll
        for (int r = 0; r < 4; r++) {
            float p = 0.f;
            #pragma unroll
            for (int nt = 0; nt < 8; nt++)
                p += fmaxf(accR[nt][r] + br1r[nt], 0.f) * wr2r[nt];
            p += __shfl_xor(p, 1, 64);
            p += __shfl_xor(p, 2, 64);
            p += __shfl_xor(p, 4, 64);
            p += __shfl_xor(p, 8, 64);
            if (l15 == 0) {
                int n = n0 + wv * 16 + quad * 4 + r;
                if (n < NN) out[n] = p + br2v;
            }
        }
    }
}

// ---------------------------------------------------------------------------
extern "C" void kernel_launch(void* const* d_in, const int* in_sizes, int n_in,
                              void* d_out, int out_size, void* d_ws, size_t ws_size,
                              hipStream_t stream)
{
    const float* nf  = (const float*)d_in[0];
    const float* ef  = (const float*)d_in[1];
    const int* esrc  = (const int*)d_in[2];
    const int* edst  = (const int*)d_in[3];
    const float* Wm1 = (const float*)d_in[4];
    const float* bm1 = (const float*)d_in[5];
    const float* Wm2 = (const float*)d_in[6];
    const float* bm2 = (const float*)d_in[7];
    const float* Wx  = (const float*)d_in[8];
    const float* Wh  = (const float*)d_in[9];
    const float* bg  = (const float*)d_in[10];
    const float* Wr1 = (const float*)d_in[11];
    const float* br1 = (const float*)d_in[12];
    const float* Wr2 = (const float*)d_in[13];
    const float* br2 = (const float*)d_in[14];

    char* ws = (char*)d_ws;
    float*  hbuf   = (float*)(ws);                   // 12,800,000
    bf16_t* hb     = (bf16_t*)(ws + 12800000);       // 6,400,000
    bf16_t* W1f    = (bf16_t*)(ws + 19200000);       // 40,960
    bf16_t* W2f    = (bf16_t*)(ws + 19240960);       // 16,384
    bf16_t* Wxt    = (bf16_t*)(ws + 19257344);       // 24,576
    bf16_t* Wht    = (bf16_t*)(ws + 19281920);       // 24,576
    bf16_t* Wr1f   = (bf16_t*)(ws + 19306496);       // 16,384
    int*    srcs   = (int*)(ws + 19322880);          // 1,600,000
    int*    dsts   = (int*)(ws + 20922880);          // 1,600,000
    bf16_t* efpb   = (bf16_t*)(ws + 22522880);       // 6,400,000
    int*    deg    = (int*)(ws + 28922880);          // 200,704
    int*    cursor = (int*)(ws + 29123584);          // 200,704
    int*    chunkS = (int*)(ws + 29324288);          // 1,024
    bf16_t* aggb   = (bf16_t*)(ws + 29326336);       // 6,400,000
    bf16_t* mb     = (bf16_t*)(ws + 35726336);       // 51,200,000

    // deg must be zero before prep's fused histogram
    hipMemsetAsync(deg, 0, (size_t)NPAD * 4, stream);
    prep_kernel<<<4928, 256, 0, stream>>>(nf, Wm1, Wm2, Wx, Wh, Wr1, edst, deg,
                                          hb, W1f, W2f, Wxt, Wht, Wr1f);

    scanA_kernel<<<NCH, 256, 0, stream>>>(deg, chunkS);
    scanC_kernel<<<NCH, 256, 0, stream>>>(deg, chunkS, cursor);
    scatter_kernel<<<(NE + 255) / 256, 256, 0, stream>>>(esrc, edst, ef, cursor,
                                                         srcs, dsts, efpb);

    // step 0
    edge_kernel<<<1024, 256, 0, stream>>>(hb, efpb, srcs, dsts,
                                          W1f, W2f, bm1, bm2, mb);
    agg_kernel<<<(NN + 3) / 4, 256, 0, stream>>>(mb, deg, cursor, aggb);
    gru_kernel<0><<<(NN + 63) / 64, 256, 0, stream>>>(
        aggb, nf, hbuf, hb, Wxt, Wht, bg, Wr1f, br1, Wr2, br2, (float*)d_out);
    // step 1
    edge_kernel<<<1024, 256, 0, stream>>>(hb, efpb, srcs, dsts,
                                          W1f, W2f, bm1, bm2, mb);
    agg_kernel<<<(NN + 3) / 4, 256, 0, stream>>>(mb, deg, cursor, aggb);
    gru_kernel<1><<<(NN + 63) / 64, 256, 0, stream>>>(
        aggb, hbuf, nullptr, nullptr, Wxt, Wht, bg, Wr1f, br1, Wr2, br2,
        (float*)d_out);
}